// Round 1
// 830.380 us; speedup vs baseline: 1.0500x; 1.0500x over previous
//
#include <hip/hip_runtime.h>

#define BATCH 32
#define SEQT 1000
#define INSZ 4
#define HID 2048
#define NOISE_STD 0.05f
#define ALPHA 0.2f
#define ONE_M_ALPHA (1.0f - ALPHA)

#define NTHREADS 512
#define NWAVES 8           // 2 waves per SIMD (R3: 1/SIMD regressed)
#define EPT 4              // HID / NTHREADS
#define PF 4               // prefetch depth (== unroll)

typedef float v2f __attribute__((ext_vector_type(2)));

// ---- forced VOP3P packed-f32 math (guard against scalarized <2 x float>) ----
__device__ __forceinline__ v2f pk_fma(v2f a, v2f b, v2f c) {
    v2f d; asm("v_pk_fma_f32 %0, %1, %2, %3" : "=v"(d) : "v"(a), "v"(b), "v"(c)); return d;
}
__device__ __forceinline__ v2f pk_mul(v2f a, v2f b) {
    v2f d; asm("v_pk_mul_f32 %0, %1, %2" : "=v"(d) : "v"(a), "v"(b)); return d;
}
__device__ __forceinline__ v2f pk_add(v2f a, v2f b) {
    v2f d; asm("v_pk_add_f32 %0, %1, %2" : "=v"(d) : "v"(a), "v"(b)); return d;
}
#define C2(v) (v2f{(v), (v)})

// ---- fused DPP reductions (single v_add_f32_dpp per level, twin-interleaved
//      so the 2-cycle VALU->DPP wait state is covered by the sibling chain;
//      leading s_nop 1 covers the entry hazard from preceding VALU writes) ----

// twin 64-lane sum trees; totals valid in lane 63 (same shr/bcast pairing as before)
__device__ __forceinline__ void tree64_pair(float& a, float& b) {
    asm("s_nop 1\n\t"
        "v_add_f32_dpp %0, %0, %0 row_shr:1 row_mask:0xf bank_mask:0xf bound_ctrl:0\n\t"
        "v_add_f32_dpp %1, %1, %1 row_shr:1 row_mask:0xf bank_mask:0xf bound_ctrl:0\n\t"
        "v_add_f32_dpp %0, %0, %0 row_shr:2 row_mask:0xf bank_mask:0xf bound_ctrl:0\n\t"
        "v_add_f32_dpp %1, %1, %1 row_shr:2 row_mask:0xf bank_mask:0xf bound_ctrl:0\n\t"
        "v_add_f32_dpp %0, %0, %0 row_shr:4 row_mask:0xf bank_mask:0xf bound_ctrl:0\n\t"
        "v_add_f32_dpp %1, %1, %1 row_shr:4 row_mask:0xf bank_mask:0xf bound_ctrl:0\n\t"
        "v_add_f32_dpp %0, %0, %0 row_shr:8 row_mask:0xf bank_mask:0xf bound_ctrl:0\n\t"
        "v_add_f32_dpp %1, %1, %1 row_shr:8 row_mask:0xf bank_mask:0xf bound_ctrl:0\n\t"
        "v_add_f32_dpp %0, %0, %0 row_bcast:15 row_mask:0xf bank_mask:0xf bound_ctrl:0\n\t"
        "v_add_f32_dpp %1, %1, %1 row_bcast:15 row_mask:0xf bank_mask:0xf bound_ctrl:0\n\t"
        "v_add_f32_dpp %0, %0, %0 row_bcast:31 row_mask:0xf bank_mask:0xf bound_ctrl:0\n\t"
        "v_add_f32_dpp %1, %1, %1 row_bcast:31 row_mask:0xf bank_mask:0xf bound_ctrl:0"
        : "+v"(a), "+v"(b));
}

// twin 8-lane butterfly: EVERY lane ends with the sum of its 8-lane group's values.
// Pairing identical to the old shr1/2/4 tree (commutations only) -> bitwise-equal y.
__device__ __forceinline__ void bfly8_pair(float& a, float& b) {
    asm("s_nop 1\n\t"
        "v_add_f32_dpp %0, %0, %0 quad_perm:[1,0,3,2] row_mask:0xf bank_mask:0xf\n\t"
        "v_add_f32_dpp %1, %1, %1 quad_perm:[1,0,3,2] row_mask:0xf bank_mask:0xf\n\t"
        "v_add_f32_dpp %0, %0, %0 quad_perm:[2,3,0,1] row_mask:0xf bank_mask:0xf\n\t"
        "v_add_f32_dpp %1, %1, %1 quad_perm:[2,3,0,1] row_mask:0xf bank_mask:0xf\n\t"
        "v_add_f32_dpp %0, %0, %0 row_half_mirror row_mask:0xf bank_mask:0xf\n\t"
        "v_add_f32_dpp %1, %1, %1 row_half_mirror row_mask:0xf bank_mask:0xf"
        : "+v"(a), "+v"(b));
}

// tanh via Pade[5/4] + clamp (unchanged math, forced packed)
__device__ __forceinline__ v2f pade_tanh(v2f x) {
    const v2f x2  = pk_mul(x, x);
    const v2f num = pk_mul(x, pk_fma(x2, pk_add(x2, C2(105.0f)), C2(945.0f)));
    const v2f den = pk_fma(x2, pk_fma(x2, C2(15.0f), C2(420.0f)), C2(945.0f));
    v2f r;
    r.x = num.x * __builtin_amdgcn_rcpf(den.x);
    r.y = num.y * __builtin_amdgcn_rcpf(den.y);
    r.x = fminf(fmaxf(r.x, -1.0f), 1.0f);   // v_med3
    r.y = fminf(fmaxf(r.y, -1.0f), 1.0f);
    return r;
}

// scalar version for init path
__device__ __forceinline__ float pade_tanh_s(float x) {
    const float x2 = x * x;
    const float num = x * fmaf(x2, x2 + 105.0f, 945.0f);
    const float den = fmaf(x2, fmaf(x2, 15.0f, 420.0f), 945.0f);
    float r = num * __builtin_amdgcn_rcpf(den);
    return fminf(fmaxf(r, -1.0f), 1.0f);
}

// LDS-only barrier: does NOT drain vmcnt (global noise prefetch stays in flight)
#define LDS_BARRIER() __asm__ volatile("s_waitcnt lgkmcnt(0)\ns_barrier" ::: "memory")

__global__ __launch_bounds__(NTHREADS)
void rnn_kernel(const float* __restrict__ input,
                const float* __restrict__ noise,
                const float* __restrict__ wi_w,
                const float* __restrict__ m_w,
                const float* __restrict__ n_w,
                const float* __restrict__ wo_w,
                const float* __restrict__ wi_b,
                const float* __restrict__ m_b,
                const float* __restrict__ n_b,
                const float* __restrict__ h0_w,
                const float* __restrict__ gb,
                const float* __restrict__ sup,
                float* __restrict__ out)
{
    // input rows pre-duplicated per component: (x,x),(y,y),(z,z),(w,w) so phase-A
    // pk operands come straight from 2x ds_read_b128 with zero broadcast movs.
    __shared__ __align__(16) float2 sDup[SEQT][4];            // 32000 B
    // wave-partial publish buffers, parity double-buffered.
    // [8][65] float2: read addr (k*520+504) -> 8 distinct bank pairs, conflict-free.
    __shared__ float2 sW[2][NWAVES][65];                      // y partials (pre-barrier)
    __shared__ float2 sO[2][NWAVES][65];                      // o partials (post-barrier)

    const int b    = blockIdx.x;
    const int tid  = threadIdx.x;
    const int wave = tid >> 6;
    const int lane = tid & 63;

    // stage + duplicate input rows into LDS
    const float4* inRow4 = reinterpret_cast<const float4*>(input + (size_t)b * SEQT * INSZ);
    for (int i = tid; i < SEQT; i += NTHREADS) {
        const float4 v = inRow4[i];
        sDup[i][0] = make_float2(v.x, v.x);
        sDup[i][1] = make_float2(v.y, v.y);
        sDup[i][2] = make_float2(v.z, v.z);
        sDup[i][3] = make_float2(v.w, v.w);
    }

    // ---- one-time proxy params; ownership h = tid*4 + e (contiguous -> coalesced noise)
    v2f wiA[INSZ][2];                // alpha * wi, packed pairs
    v2f mA0v[2], mA1v[2], n0v[2], n1v[2], wo0v[2], wo1v[2], hv[2];
    v2f q0 = {0.f, 0.f}, q1 = q0, q2 = q0, q3 = q0;  // pair partial accumulators

    #pragma unroll
    for (int e = 0; e < EPT; ++e) {
        const int h = tid * 4 + e;
        const int pi = e >> 1, pc = e & 1;
        float gv[8];
        #pragma unroll
        for (int g = 0; g < 8; ++g) gv[g] = gb[g * HID + h];
        const float s0 = sup[h];
        const float s1 = sup[HID + h];

        auto mix = [&](const float* w) -> float {
            float a0 = 0.f, a1 = 0.f;
            #pragma unroll
            for (int g = 0; g < 8; ++g) { a0 += w[g] * gv[g]; a1 += w[8 + g] * gv[g]; }
            return s0 * a0 + s1 * a1;
        };

        #pragma unroll
        for (int i = 0; i < INSZ; ++i)
            wiA[i][pi][pc] = ALPHA * (mix(wi_w + i * 16) + wi_b[i * 2 + 0] * s0 + wi_b[i * 2 + 1] * s1);
        mA0v[pi][pc] = ALPHA * (mix(m_w)      + m_b[0] * s0 + m_b[1] * s1);
        mA1v[pi][pc] = ALPHA * (mix(m_w + 16) + m_b[2] * s0 + m_b[3] * s1);
        const float n0 = mix(n_w)      + n_b[0] * s0 + n_b[1] * s1;
        const float n1 = mix(n_w + 16) + n_b[2] * s0 + n_b[3] * s1;
        const float w0 = mix(wo_w);
        const float w1 = mix(wo_w + 16);
        n0v[pi][pc] = n0;  n1v[pi][pc] = n1;
        wo0v[pi][pc] = w0; wo1v[pi][pc] = w1;
        {
            float a0 = 0.f, a1 = 0.f;
            #pragma unroll
            for (int g = 0; g < 8; ++g) { a0 += h0_w[g] * gv[g]; a1 += h0_w[8 + g] * gv[g]; }
            const float h0v = s0 * a0 + s1 * a1;
            hv[pi][pc] = h0v;
            const float r = pade_tanh_s(h0v);
            q0[pc] += r * n0;  q1[pc] += r * n1;
            q2[pc] += r * w0;  q3[pc] += r * w1;
        }
    }

    // noise: one coalesced float4 per lane per step; PF-deep register prefetch
    const float4* nP4 = reinterpret_cast<const float4*>(noise + (size_t)b * SEQT * HID);
    const int rowStride = HID / 4;
    float4 nb0 = nP4[0 * rowStride + tid];
    float4 nb1 = nP4[1 * rowStride + tid];
    float4 nb2 = nP4[2 * rowStride + tid];
    float4 nb3 = nP4[3 * rowStride + tid];

    float* outRow = out + (size_t)b * SEQT * 2;

    __syncthreads();                      // sDup ready (one full barrier)
    const float4* dRow = reinterpret_cast<const float4*>(sDup);   // 2 float4 per t
    float4 ivA0 = dRow[0], ivB0 = dRow[1];
    float4 ivA1 = dRow[2], ivB1 = dRow[3];
    float4 ivA2 = dRow[4], ivB2 = dRow[5];
    float4 ivA3 = dRow[6], ivB3 = dRow[7];

    const v2f cNS  = C2(NOISE_STD);
    const v2f cOMA = C2(ONE_M_ALPHA);

    auto do_step = [&](int t, int PAR, float4& nbuf, float4& ivAreg, float4& ivBreg) {
        // ---- pre-barrier (SHORT): y-trees + branchless all-lane publish (b64)
        float w0 = q0.x + q0.y;
        float w1 = q1.x + q1.y;
        tree64_pair(w0, w1);
        sW[PAR][wave][lane] = make_float2(w0, w1);   // readers use [slot][63] only

        LDS_BARRIER();                    // lgkm-only; vmcnt prefetches stay in flight

        // ---- post-barrier: issue the broadcast reads first, fill their latency
        const float2 prw = sW[PAR][lane & 7][63];       // y wave-partials
        const float2 pro = sO[PAR ^ 1][lane & 7][63];   // o wave-partials (1 step old)

        // filler 1: o-trees for r^{(t-1)} (current q2,q3 before phase C overwrites);
        // published POST-barrier -> off the pre-barrier lgkm critical wait.
        float oz = q2.x + q2.y;
        float ow = q3.x + q3.y;
        tree64_pair(oz, ow);
        sO[PAR][wave][lane] = make_float2(oz, ow);

        // filler 2: prefetch issues (drain at NEXT step's barrier — hidden)
        const int tpre = (t + PF < SEQT) ? (t + PF) : (SEQT - 1);
        const float4 nv4 = nbuf;
        nbuf = nP4[(size_t)tpre * rowStride + tid];     // global prefetch (vmcnt)
        const float4 ivA = ivAreg, ivB = ivBreg;
        ivAreg = dRow[2 * tpre];                        // LDS prefetch (lgkm)
        ivBreg = dRow[2 * tpre + 1];

        // filler 3: phase A (independent of y), forced packed fma
        const v2f nlo = {nv4.x, nv4.y}, nhi = {nv4.z, nv4.w};
        const v2f ix = {ivA.x, ivA.y}, iy = {ivA.z, ivA.w};
        const v2f iz = {ivB.x, ivB.y}, iw = {ivB.z, ivB.w};
        v2f acc0 = pk_mul(wiA[0][0], ix);
        v2f acc1 = pk_mul(wiA[0][1], ix);
        acc0 = pk_fma(wiA[1][0], iy, acc0);  acc1 = pk_fma(wiA[1][1], iy, acc1);
        acc0 = pk_fma(wiA[2][0], iz, acc0);  acc1 = pk_fma(wiA[2][1], iz, acc1);
        acc0 = pk_fma(wiA[3][0], iw, acc0);  acc1 = pk_fma(wiA[3][1], iw, acc1);
        acc0 = pk_fma(nlo, cNS, acc0);       acc1 = pk_fma(nhi, cNS, acc1);
        acc0 = pk_fma(hv[0], cOMA, acc0);    acc1 = pk_fma(hv[1], cOMA, acc1);

        // y: 8-lane butterfly over wave partials — every lane gets y, no readlane
        float y0 = prw.x, y1 = prw.y;
        bfly8_pair(y0, y1);

        // output row t-2 (= wo . r^{(t-2)}): unconditional butterfly (keeps DPP out of
        // exec-masked regions), single fused-predicate store
        float o0 = pro.x, o1 = pro.y;
        bfly8_pair(o0, o1);
        if (t >= 2 && tid == ((t & 7) << 6))
            *reinterpret_cast<float2*>(outRow + (t - 2) * 2) = make_float2(o0, o1);

        // ---- phase C: finish update + next partials (forced packed)
        const v2f y0p = {y0, y0}, y1p = {y1, y1};
        v2f h2a = pk_fma(mA1v[0], y1p, acc0);
        v2f h2b = pk_fma(mA1v[1], y1p, acc1);
        h2a = pk_fma(mA0v[0], y0p, h2a);
        h2b = pk_fma(mA0v[1], y0p, h2b);
        hv[0] = h2a; hv[1] = h2b;
        const v2f r2a = pade_tanh(h2a);
        const v2f r2b = pade_tanh(h2b);
        q0 = pk_fma(r2b, n0v[1],  pk_mul(r2a, n0v[0]));
        q1 = pk_fma(r2b, n1v[1],  pk_mul(r2a, n1v[0]));
        q2 = pk_fma(r2b, wo0v[1], pk_mul(r2a, wo0v[0]));
        q3 = pk_fma(r2b, wo1v[1], pk_mul(r2a, wo1v[0]));
    };

    for (int t = 0; t < SEQT; t += PF) {
        do_step(t,     0, nb0, ivA0, ivB0);
        do_step(t + 1, 1, nb1, ivA1, ivB1);
        do_step(t + 2, 0, nb2, ivA2, ivB2);
        do_step(t + 3, 1, nb3, ivA3, ivB3);
    }

    // epilogue: row 998 (= sO[1], published at t=999) and row 999 (= final q2,q3)
    {
        float a9 = q2.x + q2.y;
        float b9 = q3.x + q3.y;
        tree64_pair(a9, b9);
        sW[0][wave][lane] = make_float2(a9, b9);
        LDS_BARRIER();
        const float2 pr9 = sW[0][lane & 7][63];
        const float2 pr8 = sO[1][lane & 7][63];
        float x9 = pr9.x, y9 = pr9.y;
        float x8 = pr8.x, y8 = pr8.y;
        bfly8_pair(x9, y9);
        bfly8_pair(x8, y8);
        if (tid == 0) {
            *reinterpret_cast<float2*>(outRow + 998 * 2) = make_float2(x8, y8);
            *reinterpret_cast<float2*>(outRow + 999 * 2) = make_float2(x9, y9);
        }
    }
}

extern "C" void kernel_launch(void* const* d_in, const int* in_sizes, int n_in,
                              void* d_out, int out_size, void* d_ws, size_t ws_size,
                              hipStream_t stream) {
    const float* input = (const float*)d_in[0];
    const float* noise = (const float*)d_in[1];
    const float* wi_w  = (const float*)d_in[2];
    const float* m_w   = (const float*)d_in[3];
    const float* n_w   = (const float*)d_in[4];
    const float* wo_w  = (const float*)d_in[5];
    const float* wi_b  = (const float*)d_in[6];
    const float* m_b   = (const float*)d_in[7];
    const float* n_b   = (const float*)d_in[8];
    const float* h0_w  = (const float*)d_in[9];
    const float* gb    = (const float*)d_in[10];
    const float* sup   = (const float*)d_in[11];
    float* out = (float*)d_out;

    rnn_kernel<<<dim3(BATCH), dim3(NTHREADS), 0, stream>>>(
        input, noise, wi_w, m_w, n_w, wo_w, wi_b, m_b, n_b, h0_w, gb, sup, out);
}

// Round 2
// 800.653 us; speedup vs baseline: 1.0890x; 1.0371x over previous
//
#include <hip/hip_runtime.h>

#define BATCH 32
#define SEQT 1000
#define INSZ 4
#define HID 2048
#define NOISE_STD 0.05f
#define ALPHA 0.2f
#define ONE_M_ALPHA (1.0f - ALPHA)

#define NTHREADS 256
#define NWAVES 4           // 1 wave per SIMD; per-SIMD issue load -33% vs 8x EPT4
#define EPT 8              // HID / NTHREADS
#define NPAIR 4            // EPT / 2
#define PF 4               // prefetch depth (== unroll)

typedef float v2f __attribute__((ext_vector_type(2)));

// ---- forced VOP3P packed-f32 math ----
__device__ __forceinline__ v2f pk_fma(v2f a, v2f b, v2f c) {
    v2f d; asm("v_pk_fma_f32 %0, %1, %2, %3" : "=v"(d) : "v"(a), "v"(b), "v"(c)); return d;
}
__device__ __forceinline__ v2f pk_mul(v2f a, v2f b) {
    v2f d; asm("v_pk_mul_f32 %0, %1, %2" : "=v"(d) : "v"(a), "v"(b)); return d;
}
__device__ __forceinline__ v2f pk_add(v2f a, v2f b) {
    v2f d; asm("v_pk_add_f32 %0, %1, %2" : "=v"(d) : "v"(a), "v"(b)); return d;
}
#define C2(v) (v2f{(v), (v)})

// ---- fused DPP reductions ----
// quad-interleaved 64-lane tree: 4 independent chains, spacing 3 -> no hazard
// bubbles; totals valid in lane 63 of each chain.
__device__ __forceinline__ void tree64_quad(float& a, float& b, float& c, float& d) {
    asm("s_nop 1\n\t"
        "v_add_f32_dpp %0, %0, %0 row_shr:1 row_mask:0xf bank_mask:0xf bound_ctrl:0\n\t"
        "v_add_f32_dpp %1, %1, %1 row_shr:1 row_mask:0xf bank_mask:0xf bound_ctrl:0\n\t"
        "v_add_f32_dpp %2, %2, %2 row_shr:1 row_mask:0xf bank_mask:0xf bound_ctrl:0\n\t"
        "v_add_f32_dpp %3, %3, %3 row_shr:1 row_mask:0xf bank_mask:0xf bound_ctrl:0\n\t"
        "v_add_f32_dpp %0, %0, %0 row_shr:2 row_mask:0xf bank_mask:0xf bound_ctrl:0\n\t"
        "v_add_f32_dpp %1, %1, %1 row_shr:2 row_mask:0xf bank_mask:0xf bound_ctrl:0\n\t"
        "v_add_f32_dpp %2, %2, %2 row_shr:2 row_mask:0xf bank_mask:0xf bound_ctrl:0\n\t"
        "v_add_f32_dpp %3, %3, %3 row_shr:2 row_mask:0xf bank_mask:0xf bound_ctrl:0\n\t"
        "v_add_f32_dpp %0, %0, %0 row_shr:4 row_mask:0xf bank_mask:0xf bound_ctrl:0\n\t"
        "v_add_f32_dpp %1, %1, %1 row_shr:4 row_mask:0xf bank_mask:0xf bound_ctrl:0\n\t"
        "v_add_f32_dpp %2, %2, %2 row_shr:4 row_mask:0xf bank_mask:0xf bound_ctrl:0\n\t"
        "v_add_f32_dpp %3, %3, %3 row_shr:4 row_mask:0xf bank_mask:0xf bound_ctrl:0\n\t"
        "v_add_f32_dpp %0, %0, %0 row_shr:8 row_mask:0xf bank_mask:0xf bound_ctrl:0\n\t"
        "v_add_f32_dpp %1, %1, %1 row_shr:8 row_mask:0xf bank_mask:0xf bound_ctrl:0\n\t"
        "v_add_f32_dpp %2, %2, %2 row_shr:8 row_mask:0xf bank_mask:0xf bound_ctrl:0\n\t"
        "v_add_f32_dpp %3, %3, %3 row_shr:8 row_mask:0xf bank_mask:0xf bound_ctrl:0\n\t"
        "v_add_f32_dpp %0, %0, %0 row_bcast:15 row_mask:0xf bank_mask:0xf bound_ctrl:0\n\t"
        "v_add_f32_dpp %1, %1, %1 row_bcast:15 row_mask:0xf bank_mask:0xf bound_ctrl:0\n\t"
        "v_add_f32_dpp %2, %2, %2 row_bcast:15 row_mask:0xf bank_mask:0xf bound_ctrl:0\n\t"
        "v_add_f32_dpp %3, %3, %3 row_bcast:15 row_mask:0xf bank_mask:0xf bound_ctrl:0\n\t"
        "v_add_f32_dpp %0, %0, %0 row_bcast:31 row_mask:0xf bank_mask:0xf bound_ctrl:0\n\t"
        "v_add_f32_dpp %1, %1, %1 row_bcast:31 row_mask:0xf bank_mask:0xf bound_ctrl:0\n\t"
        "v_add_f32_dpp %2, %2, %2 row_bcast:31 row_mask:0xf bank_mask:0xf bound_ctrl:0\n\t"
        "v_add_f32_dpp %3, %3, %3 row_bcast:31 row_mask:0xf bank_mask:0xf bound_ctrl:0"
        : "+v"(a), "+v"(b), "+v"(c), "+v"(d));
}

// pair version (epilogue only)
__device__ __forceinline__ void tree64_pair(float& a, float& b) {
    asm("s_nop 1\n\t"
        "v_add_f32_dpp %0, %0, %0 row_shr:1 row_mask:0xf bank_mask:0xf bound_ctrl:0\n\t"
        "v_add_f32_dpp %1, %1, %1 row_shr:1 row_mask:0xf bank_mask:0xf bound_ctrl:0\n\t"
        "v_add_f32_dpp %0, %0, %0 row_shr:2 row_mask:0xf bank_mask:0xf bound_ctrl:0\n\t"
        "v_add_f32_dpp %1, %1, %1 row_shr:2 row_mask:0xf bank_mask:0xf bound_ctrl:0\n\t"
        "v_add_f32_dpp %0, %0, %0 row_shr:4 row_mask:0xf bank_mask:0xf bound_ctrl:0\n\t"
        "v_add_f32_dpp %1, %1, %1 row_shr:4 row_mask:0xf bank_mask:0xf bound_ctrl:0\n\t"
        "v_add_f32_dpp %0, %0, %0 row_shr:8 row_mask:0xf bank_mask:0xf bound_ctrl:0\n\t"
        "v_add_f32_dpp %1, %1, %1 row_shr:8 row_mask:0xf bank_mask:0xf bound_ctrl:0\n\t"
        "v_add_f32_dpp %0, %0, %0 row_bcast:15 row_mask:0xf bank_mask:0xf bound_ctrl:0\n\t"
        "v_add_f32_dpp %1, %1, %1 row_bcast:15 row_mask:0xf bank_mask:0xf bound_ctrl:0\n\t"
        "v_add_f32_dpp %0, %0, %0 row_bcast:31 row_mask:0xf bank_mask:0xf bound_ctrl:0\n\t"
        "v_add_f32_dpp %1, %1, %1 row_bcast:31 row_mask:0xf bank_mask:0xf bound_ctrl:0"
        : "+v"(a), "+v"(b));
}

// 4-slot butterfly (4 wave-partials live in slots lane&3): 2 levels, every lane
// in each quad ends with the total. Commutative pairing -> identical bits/lane.
__device__ __forceinline__ void bfly4_quad(float& a, float& b, float& c, float& d) {
    asm("s_nop 1\n\t"
        "v_add_f32_dpp %0, %0, %0 quad_perm:[1,0,3,2] row_mask:0xf bank_mask:0xf\n\t"
        "v_add_f32_dpp %1, %1, %1 quad_perm:[1,0,3,2] row_mask:0xf bank_mask:0xf\n\t"
        "v_add_f32_dpp %2, %2, %2 quad_perm:[1,0,3,2] row_mask:0xf bank_mask:0xf\n\t"
        "v_add_f32_dpp %3, %3, %3 quad_perm:[1,0,3,2] row_mask:0xf bank_mask:0xf\n\t"
        "v_add_f32_dpp %0, %0, %0 quad_perm:[2,3,0,1] row_mask:0xf bank_mask:0xf\n\t"
        "v_add_f32_dpp %1, %1, %1 quad_perm:[2,3,0,1] row_mask:0xf bank_mask:0xf\n\t"
        "v_add_f32_dpp %2, %2, %2 quad_perm:[2,3,0,1] row_mask:0xf bank_mask:0xf\n\t"
        "v_add_f32_dpp %3, %3, %3 quad_perm:[2,3,0,1] row_mask:0xf bank_mask:0xf"
        : "+v"(a), "+v"(b), "+v"(c), "+v"(d));
}

__device__ __forceinline__ void bfly4_pair(float& a, float& b) {
    asm("s_nop 1\n\t"
        "v_add_f32_dpp %0, %0, %0 quad_perm:[1,0,3,2] row_mask:0xf bank_mask:0xf\n\t"
        "v_add_f32_dpp %1, %1, %1 quad_perm:[1,0,3,2] row_mask:0xf bank_mask:0xf\n\t"
        "v_add_f32_dpp %0, %0, %0 quad_perm:[2,3,0,1] row_mask:0xf bank_mask:0xf\n\t"
        "v_add_f32_dpp %1, %1, %1 quad_perm:[2,3,0,1] row_mask:0xf bank_mask:0xf"
        : "+v"(a), "+v"(b));
}

// tanh via Pade[5/4] + clamp (unchanged math)
__device__ __forceinline__ v2f pade_tanh(v2f x) {
    const v2f x2  = pk_mul(x, x);
    const v2f num = pk_mul(x, pk_fma(x2, pk_add(x2, C2(105.0f)), C2(945.0f)));
    const v2f den = pk_fma(x2, pk_fma(x2, C2(15.0f), C2(420.0f)), C2(945.0f));
    v2f r;
    r.x = num.x * __builtin_amdgcn_rcpf(den.x);
    r.y = num.y * __builtin_amdgcn_rcpf(den.y);
    r.x = fminf(fmaxf(r.x, -1.0f), 1.0f);
    r.y = fminf(fmaxf(r.y, -1.0f), 1.0f);
    return r;
}

__device__ __forceinline__ float pade_tanh_s(float x) {
    const float x2 = x * x;
    const float num = x * fmaf(x2, x2 + 105.0f, 945.0f);
    const float den = fmaf(x2, fmaf(x2, 15.0f, 420.0f), 945.0f);
    float r = num * __builtin_amdgcn_rcpf(den);
    return fminf(fmaxf(r, -1.0f), 1.0f);
}

// LDS-only barrier: does NOT drain vmcnt (global noise prefetch stays in flight)
#define LDS_BARRIER() __asm__ volatile("s_waitcnt lgkmcnt(0)\ns_barrier" ::: "memory")

__global__ __launch_bounds__(NTHREADS)
void rnn_kernel(const float* __restrict__ input,
                const float* __restrict__ noise,
                const float* __restrict__ wi_w,
                const float* __restrict__ m_w,
                const float* __restrict__ n_w,
                const float* __restrict__ wo_w,
                const float* __restrict__ wi_b,
                const float* __restrict__ m_b,
                const float* __restrict__ n_b,
                const float* __restrict__ h0_w,
                const float* __restrict__ gb,
                const float* __restrict__ sup,
                float* __restrict__ out)
{
    // input rows pre-duplicated per component so phase-A pk operands come
    // straight from 2x ds_read_b128 with zero broadcast movs.
    __shared__ __align__(16) float2 sDup[SEQT][4];            // 32000 B
    // single fused publish buffer: (y0,y1,o0,o1) per wave, parity dbuf.
    // [4][65] float4: read addr banks {28,0,4,8} -> conflict-free broadcast.
    __shared__ __align__(16) float4 sW4[2][NWAVES][65];       // 8320 B

    const int b    = blockIdx.x;
    const int tid  = threadIdx.x;
    const int wave = tid >> 6;
    const int lane = tid & 63;

    // stage + duplicate input rows into LDS
    const float4* inRow4 = reinterpret_cast<const float4*>(input + (size_t)b * SEQT * INSZ);
    for (int i = tid; i < SEQT; i += NTHREADS) {
        const float4 v = inRow4[i];
        sDup[i][0] = make_float2(v.x, v.x);
        sDup[i][1] = make_float2(v.y, v.y);
        sDup[i][2] = make_float2(v.z, v.z);
        sDup[i][3] = make_float2(v.w, v.w);
    }

    // ---- one-time proxy params; ownership h = tid*8 + e (contiguous -> coalesced noise)
    v2f wiA[INSZ][NPAIR];
    v2f mA0v[NPAIR], mA1v[NPAIR], n0v[NPAIR], n1v[NPAIR], wo0v[NPAIR], wo1v[NPAIR], hv[NPAIR];
    v2f q0 = {0.f, 0.f}, q1 = q0, q2 = q0, q3 = q0;

    #pragma unroll
    for (int e = 0; e < EPT; ++e) {
        const int h = tid * EPT + e;
        const int pi = e >> 1, pc = e & 1;
        float gv[8];
        #pragma unroll
        for (int g = 0; g < 8; ++g) gv[g] = gb[g * HID + h];
        const float s0 = sup[h];
        const float s1 = sup[HID + h];

        auto mix = [&](const float* w) -> float {
            float a0 = 0.f, a1 = 0.f;
            #pragma unroll
            for (int g = 0; g < 8; ++g) { a0 += w[g] * gv[g]; a1 += w[8 + g] * gv[g]; }
            return s0 * a0 + s1 * a1;
        };

        #pragma unroll
        for (int i = 0; i < INSZ; ++i)
            wiA[i][pi][pc] = ALPHA * (mix(wi_w + i * 16) + wi_b[i * 2 + 0] * s0 + wi_b[i * 2 + 1] * s1);
        mA0v[pi][pc] = ALPHA * (mix(m_w)      + m_b[0] * s0 + m_b[1] * s1);
        mA1v[pi][pc] = ALPHA * (mix(m_w + 16) + m_b[2] * s0 + m_b[3] * s1);
        const float n0 = mix(n_w)      + n_b[0] * s0 + n_b[1] * s1;
        const float n1 = mix(n_w + 16) + n_b[2] * s0 + n_b[3] * s1;
        const float w0 = mix(wo_w);
        const float w1 = mix(wo_w + 16);
        n0v[pi][pc] = n0;  n1v[pi][pc] = n1;
        wo0v[pi][pc] = w0; wo1v[pi][pc] = w1;
        {
            float a0 = 0.f, a1 = 0.f;
            #pragma unroll
            for (int g = 0; g < 8; ++g) { a0 += h0_w[g] * gv[g]; a1 += h0_w[8 + g] * gv[g]; }
            const float h0v = s0 * a0 + s1 * a1;
            hv[pi][pc] = h0v;
            const float r = pade_tanh_s(h0v);
            q0[pc] += r * n0;  q1[pc] += r * n1;
            q2[pc] += r * w0;  q3[pc] += r * w1;
        }
    }

    // noise: 2 coalesced float4 per lane per step (32 B); PF-deep register prefetch
    const float4* nP4 = reinterpret_cast<const float4*>(noise + (size_t)b * SEQT * HID);
    const int rowStride = HID / 4;   // 512
    const int nbase = tid * 2;
    float4 na0 = nP4[0 * rowStride + nbase], nb0 = nP4[0 * rowStride + nbase + 1];
    float4 na1 = nP4[1 * rowStride + nbase], nb1 = nP4[1 * rowStride + nbase + 1];
    float4 na2 = nP4[2 * rowStride + nbase], nb2 = nP4[2 * rowStride + nbase + 1];
    float4 na3 = nP4[3 * rowStride + nbase], nb3 = nP4[3 * rowStride + nbase + 1];

    float* outRow = out + (size_t)b * SEQT * 2;

    __syncthreads();                      // sDup ready (one full barrier)
    const float4* dRow = reinterpret_cast<const float4*>(sDup);   // 2 float4 per t
    float4 ivA0 = dRow[0], ivB0 = dRow[1];
    float4 ivA1 = dRow[2], ivB1 = dRow[3];
    float4 ivA2 = dRow[4], ivB2 = dRow[5];
    float4 ivA3 = dRow[6], ivB3 = dRow[7];

    const v2f cNS  = C2(NOISE_STD);
    const v2f cOMA = C2(ONE_M_ALPHA);

    auto do_step = [&](int t, int PAR, float4& nA, float4& nB, float4& ivAreg, float4& ivBreg) {
        // ---- pre-barrier: fused quad tree (y0,y1,o0,o1) + ONE b128 publish
        float w0 = q0.x + q0.y;
        float w1 = q1.x + q1.y;
        float oz = q2.x + q2.y;
        float ow = q3.x + q3.y;
        tree64_quad(w0, w1, oz, ow);
        sW4[PAR][wave][lane] = make_float4(w0, w1, oz, ow);  // readers use [slot][63]

        LDS_BARRIER();                    // lgkm-only; vmcnt prefetches stay in flight

        // ---- post-barrier: issue the broadcast read first, fill its latency
        const float4 pr = sW4[PAR][lane & 3][63];

        // filler 1: prefetch issues (drain at NEXT step's barrier — hidden)
        const int tpre = (t + PF < SEQT) ? (t + PF) : (SEQT - 1);
        const float4 nv4a = nA, nv4b = nB;
        nA = nP4[(size_t)tpre * rowStride + nbase];          // global prefetch (vmcnt)
        nB = nP4[(size_t)tpre * rowStride + nbase + 1];
        const float4 ivA = ivAreg, ivB = ivBreg;
        ivAreg = dRow[2 * tpre];                             // LDS prefetch (lgkm)
        ivBreg = dRow[2 * tpre + 1];

        // filler 2: phase A (independent of y), forced packed fma
        const v2f ix = {ivA.x, ivA.y}, iy = {ivA.z, ivA.w};
        const v2f iz = {ivB.x, ivB.y}, iw = {ivB.z, ivB.w};
        const v2f nn[NPAIR] = { {nv4a.x, nv4a.y}, {nv4a.z, nv4a.w},
                                {nv4b.x, nv4b.y}, {nv4b.z, nv4b.w} };
        v2f acc[NPAIR];
        #pragma unroll
        for (int p = 0; p < NPAIR; ++p) {
            acc[p] = pk_mul(wiA[0][p], ix);
            acc[p] = pk_fma(wiA[1][p], iy, acc[p]);
            acc[p] = pk_fma(wiA[2][p], iz, acc[p]);
            acc[p] = pk_fma(wiA[3][p], iw, acc[p]);
            acc[p] = pk_fma(nn[p], cNS, acc[p]);
            acc[p] = pk_fma(hv[p], cOMA, acc[p]);
        }

        // y + o: one fused 2-level butterfly over the 4 wave partials
        float y0 = pr.x, y1 = pr.y, o0 = pr.z, o1 = pr.w;
        bfly4_quad(y0, y1, o0, o1);

        // output row t-1 (o-partials are same-step now): designated wave, lane 0
        if (t >= 1 && tid == ((t & 3) << 6))
            *reinterpret_cast<float2*>(outRow + (t - 1) * 2) = make_float2(o0, o1);

        // ---- phase C: finish update + next partials (forced packed)
        const v2f y0p = {y0, y0}, y1p = {y1, y1};
        v2f r[NPAIR];
        #pragma unroll
        for (int p = 0; p < NPAIR; ++p) {
            v2f h2 = pk_fma(mA1v[p], y1p, acc[p]);
            h2 = pk_fma(mA0v[p], y0p, h2);
            hv[p] = h2;
            r[p] = pade_tanh(h2);
        }
        q0 = pk_mul(r[0], n0v[0]);  q1 = pk_mul(r[0], n1v[0]);
        q2 = pk_mul(r[0], wo0v[0]); q3 = pk_mul(r[0], wo1v[0]);
        #pragma unroll
        for (int p = 1; p < NPAIR; ++p) {
            q0 = pk_fma(r[p], n0v[p],  q0);
            q1 = pk_fma(r[p], n1v[p],  q1);
            q2 = pk_fma(r[p], wo0v[p], q2);
            q3 = pk_fma(r[p], wo1v[p], q3);
        }
    };

    for (int t = 0; t < SEQT; t += PF) {
        do_step(t,     0, na0, nb0, ivA0, ivB0);
        do_step(t + 1, 1, na1, nb1, ivA1, ivB1);
        do_step(t + 2, 0, na2, nb2, ivA2, ivB2);
        do_step(t + 3, 1, na3, nb3, ivA3, ivB3);
    }

    // epilogue: row 999 = wo . r^{(999)} from final q2,q3
    {
        float a9 = q2.x + q2.y;
        float b9 = q3.x + q3.y;
        tree64_pair(a9, b9);
        sW4[0][wave][lane] = make_float4(a9, b9, 0.f, 0.f);
        LDS_BARRIER();
        const float4 pr = sW4[0][lane & 3][63];
        float x9 = pr.x, y9 = pr.y;
        bfly4_pair(x9, y9);
        if (tid == 0)
            *reinterpret_cast<float2*>(outRow + 999 * 2) = make_float2(x9, y9);
    }
}

extern "C" void kernel_launch(void* const* d_in, const int* in_sizes, int n_in,
                              void* d_out, int out_size, void* d_ws, size_t ws_size,
                              hipStream_t stream) {
    const float* input = (const float*)d_in[0];
    const float* noise = (const float*)d_in[1];
    const float* wi_w  = (const float*)d_in[2];
    const float* m_w   = (const float*)d_in[3];
    const float* n_w   = (const float*)d_in[4];
    const float* wo_w  = (const float*)d_in[5];
    const float* wi_b  = (const float*)d_in[6];
    const float* m_b   = (const float*)d_in[7];
    const float* n_b   = (const float*)d_in[8];
    const float* h0_w  = (const float*)d_in[9];
    const float* gb    = (const float*)d_in[10];
    const float* sup   = (const float*)d_in[11];
    float* out = (float*)d_out;

    rnn_kernel<<<dim3(BATCH), dim3(NTHREADS), 0, stream>>>(
        input, noise, wi_w, m_w, n_w, wo_w, wi_b, m_b, n_b, h0_w, gb, sup, out);
}